// Round 12
// baseline (124.706 us; speedup 1.0000x reference)
//
#include <hip/hip_runtime.h>
#include <hip/hip_bf16.h>

typedef unsigned short u16;
typedef __attribute__((ext_vector_type(8))) short short8;
typedef __attribute__((ext_vector_type(4))) float f32x4;

#define H 8
#define N 384
#define D 32
#define CIN 256
#define HNN (H * N * N)
#define SCALER 0.17677669529663687f
#define EPS 1e-9f

// workspace float offsets
#define PROJ_OFF 0u              // 5*H*N*D = 491520: a,b,c,vj,vk as [5][H][N][D]
#define S_OFF    491520u         // 3*H*N*N: t=0 XT[k][j], t=1 YT[i][k], t=2 Z[i][j]
#define VJT_OFF  4030464u        // H*D*N = 98304: vj transposed [h][d][n]
#define VKT_OFF  4128768u        // H*D*N
#define MX_OFF   4227072u        // 8
#define MY_OFF   4227080u        // H*N
#define MZ_OFF   4230152u        // H*N
#define NUM_OFF  4233224u        // H*N*D
#define DEN_OFF  4331528u        // H*N
#define XBF_OFF  4334600u        // ushort[H*N*N] = 589824 float slots (XT bf16)
#define ZBF_OFF  4924424u        // ushort[H*N*N] (Z bf16)
#define MXROW_OFF 5514248u       // H*N row maxima of X plane

__device__ inline float bf2f(u16 u) {
    union { unsigned int x; float f; } c; c.x = ((unsigned int)u) << 16; return c.f;
}
__device__ inline u16 f2bf(float f) {
    unsigned int x = __float_as_uint(f);
    return (u16)((x + 0x7FFFu + ((x >> 16) & 1u)) >> 16);
}

// ---------------- K1: projection GEMM  wx[n,m] = sum_k hs[n,k]*W[m,k] ----------------
__global__ __launch_bounds__(256) void proj_kernel(const float* __restrict__ hs,
                                                   const float* __restrict__ W,
                                                   float* __restrict__ proj,
                                                   float* __restrict__ projT) {
    __shared__ float hs_s[64][68];
    __shared__ float w_s[64][68];
    const int tid = threadIdx.x;
    const int tx = tid & 15, ty = tid >> 4;
    const int m0 = blockIdx.x * 64, n0 = blockIdx.y * 64;
    float acc[4][4] = {};
    for (int k0 = 0; k0 < CIN; k0 += 64) {
        __syncthreads();
#pragma unroll
        for (int rep = 0; rep < 4; ++rep) {
            int lin = rep * 1024 + tid * 4;
            int rl = lin >> 6, kl = lin & 63;
            float4 hv = *(const float4*)&hs[(n0 + rl) * CIN + k0 + kl];
            hs_s[kl + 0][rl] = hv.x; hs_s[kl + 1][rl] = hv.y;
            hs_s[kl + 2][rl] = hv.z; hs_s[kl + 3][rl] = hv.w;
            float4 wv = *(const float4*)&W[(m0 + rl) * CIN + k0 + kl];
            w_s[kl + 0][rl] = wv.x; w_s[kl + 1][rl] = wv.y;
            w_s[kl + 2][rl] = wv.z; w_s[kl + 3][rl] = wv.w;
        }
        __syncthreads();
#pragma unroll 16
        for (int kk = 0; kk < 64; ++kk) {
            float4 a4 = *(const float4*)&hs_s[kk][ty * 4];
            float4 b4 = *(const float4*)&w_s[kk][tx * 4];
            float av[4] = {a4.x, a4.y, a4.z, a4.w};
            float bv[4] = {b4.x, b4.y, b4.z, b4.w};
#pragma unroll
            for (int a_ = 0; a_ < 4; ++a_) {
#pragma unroll
                for (int b_ = 0; b_ < 4; ++b_) {
                    acc[a_][b_] = fmaf(av[a_], bv[b_], acc[a_][b_]);
                }
            }
        }
    }
#pragma unroll
    for (int a_ = 0; a_ < 4; ++a_) {
        int n = n0 + ty * 4 + a_;
#pragma unroll
        for (int b_ = 0; b_ < 4; ++b_) {
            int m = m0 + tx * 4 + b_;
            int s = m >> 8, hh = (m >> 5) & 7, d = m & 31;
            proj[s * (H * N * D) + hh * (N * D) + n * D + d] = acc[a_][b_];
            if (s >= 3) projT[(s - 3) * (H * D * N) + hh * (D * N) + d * N + n] = acc[a_][b_];
        }
    }
}

// ---------------- K2: scores ----------------
// t=0: XT[k,j] = c_k . b_j ; t=1: YT[i,k] = a_i . c_k ; t=2: Z[i,j] = a_i . b_j
// one 64x64 tile per block
__global__ __launch_bounds__(256) void scores_kernel(const float* __restrict__ proj,
                                                     float* __restrict__ S) {
    __shared__ float LsT[32][68];
    __shared__ float RsT[32][68];
    const int tid = threadIdx.x, tx = tid & 15, ty = tid >> 4;
    const int rt = blockIdx.x % 6, ct = blockIdx.x / 6;
    const int r0 = rt * 64, c0 = ct * 64;
    const int h = blockIdx.y;
    const int t = blockIdx.z;
    const int Lidx = (t == 0) ? 2 : 0;
    const int Ridx = (t == 1) ? 2 : 1;
    const float* Lp = proj + Lidx * (H * N * D) + h * (N * D);
    const float* Rp = proj + Ridx * (H * N * D) + h * (N * D);
    float* Sp = S + t * HNN + h * (N * N);
    {
        int i = tid >> 2, d8 = (tid & 3) * 8;
        float4 v0 = *(const float4*)&Lp[(r0 + i) * D + d8];
        float4 v1 = *(const float4*)&Lp[(r0 + i) * D + d8 + 4];
        LsT[d8 + 0][i] = v0.x; LsT[d8 + 1][i] = v0.y; LsT[d8 + 2][i] = v0.z; LsT[d8 + 3][i] = v0.w;
        LsT[d8 + 4][i] = v1.x; LsT[d8 + 5][i] = v1.y; LsT[d8 + 6][i] = v1.z; LsT[d8 + 7][i] = v1.w;
        float4 w0 = *(const float4*)&Rp[(c0 + i) * D + d8];
        float4 w1 = *(const float4*)&Rp[(c0 + i) * D + d8 + 4];
        RsT[d8 + 0][i] = w0.x; RsT[d8 + 1][i] = w0.y; RsT[d8 + 2][i] = w0.z; RsT[d8 + 3][i] = w0.w;
        RsT[d8 + 4][i] = w1.x; RsT[d8 + 5][i] = w1.y; RsT[d8 + 6][i] = w1.z; RsT[d8 + 7][i] = w1.w;
    }
    __syncthreads();
    float acc[4][4] = {};
#pragma unroll
    for (int dd = 0; dd < 32; ++dd) {
        float4 l4 = *(const float4*)&LsT[dd][ty * 4];
        float4 r4 = *(const float4*)&RsT[dd][tx * 4];
        float lv[4] = {l4.x, l4.y, l4.z, l4.w};
        float rv[4] = {r4.x, r4.y, r4.z, r4.w};
#pragma unroll
        for (int a_ = 0; a_ < 4; ++a_) {
#pragma unroll
            for (int b_ = 0; b_ < 4; ++b_) {
                acc[a_][b_] = fmaf(lv[a_], rv[b_], acc[a_][b_]);
            }
        }
    }
#pragma unroll
    for (int a_ = 0; a_ < 4; ++a_) {
        float4 o;
        o.x = acc[a_][0] * SCALER; o.y = acc[a_][1] * SCALER;
        o.z = acc[a_][2] * SCALER; o.w = acc[a_][3] * SCALER;
        *(float4*)&Sp[(r0 + ty * 4 + a_) * N + c0 + tx * 4] = o;
    }
}

// ---------------- K3: row maxima for all three planes ----------------
__global__ void rowmax_kernel(const float* __restrict__ S, float* __restrict__ mXrow,
                              float* __restrict__ mY, float* __restrict__ mZ) {
    const int z = blockIdx.z;
    const int h = blockIdx.y;
    const int r = blockIdx.x * 4 + (threadIdx.x >> 6);
    const int lane = threadIdx.x & 63;
    const float* row = S + z * HNN + h * (N * N) + r * N;
    float m = -3.0e38f;
    for (int q = lane; q < N; q += 64) m = fmaxf(m, row[q]);
#pragma unroll
    for (int off = 32; off; off >>= 1) m = fmaxf(m, __shfl_down(m, off));
    if (lane == 0) (z == 0 ? mXrow : (z == 1 ? mY : mZ))[h * N + r] = m;
}

// reduce mXrow[h][0..N) -> mX[h]; grid 8 x 64 threads
__global__ void reduce_mx_kernel(const float* __restrict__ mXrow, float* __restrict__ mX) {
    const int h = blockIdx.x;
    const int lane = threadIdx.x;
    float m = -3.0e38f;
    for (int q = lane; q < N; q += 64) m = fmaxf(m, mXrow[h * N + q]);
#pragma unroll
    for (int off = 32; off; off >>= 1) m = fmaxf(m, __shfl_down(m, off));
    if (lane == 0) mX[h] = m;
}

// ---------------- K4: exp.  t=1 writes f32 in place; t=0/2 write bf16 copies ----------------
__global__ void exp_kernel(float* __restrict__ S, const float* __restrict__ mX,
                           const float* __restrict__ mY, const float* __restrict__ mZ,
                           u16* __restrict__ Xbf, u16* __restrict__ Zbf) {
    int f8 = blockIdx.x * 256 + threadIdx.x;  // 442368 total
    int flat = f8 * 8;
    int t = flat / HNN;
    int rem = flat - t * HNN;
    int h = rem / (N * N);
    int rc = rem - h * (N * N);
    int r = rc / N;
    float m = (t == 0) ? mX[h] : ((t == 1) ? mY[h * N + r] : mZ[h * N + r]);
    float4 v0 = *(float4*)&S[flat];
    float4 v1 = *(float4*)&S[flat + 4];
    float e[8] = {__expf(v0.x - m), __expf(v0.y - m), __expf(v0.z - m), __expf(v0.w - m),
                  __expf(v1.x - m), __expf(v1.y - m), __expf(v1.z - m), __expf(v1.w - m)};
    if (t == 1) {
        float4 o0 = {e[0], e[1], e[2], e[3]}, o1 = {e[4], e[5], e[6], e[7]};
        *(float4*)&S[flat] = o0;
        *(float4*)&S[flat + 4] = o1;
    } else {
        short8 ov;
#pragma unroll
        for (int q = 0; q < 8; ++q) ov[q] = (short)f2bf(e[q]);
        u16* dst = (t == 0 ? Xbf : Zbf) + h * (N * N) + rc;
        *(short8*)dst = ov;
    }
}

// ---------------- K5: cubic contraction via MFMA bf16, v10 (B-side vj scaling) ----------------
// block = (h, i-tile of 64, d-group of 2). ONE raw-Z tile in LDS (48 KB); vj scaling
// moved to the B fragments in registers (vj from L1-hot broadcast loads).
// Per js per wave: 4 A LDS reads (was 8) + 2 B global + 4 vj loads + 16 MFMAs.
// LDS traffic/js/CU halves vs r11 (96->48 KB) with NO extra global B requests.
// 768 thr = 12 waves, wave owns 32 k. Regs ~140 <= 170 (768,3) -> no spill.
__global__ __launch_bounds__(768, 3) void cubic_mfma(
        const u16* __restrict__ Xbf, const u16* __restrict__ Zbf,
        const float* __restrict__ Yt, const float* __restrict__ vjT,
        const float* __restrict__ vkT, float* __restrict__ NumB,
        float* __restrict__ DenB) {
    const int orig = blockIdx.x;             // 0..815 (816 = 8 x 102, bijective)
    const int wg = (orig & 7) * 102 + (orig >> 3);
    const int h   = wg / 102;                // one head per XCD
    const int rem = wg - h * 102;
    const int dg  = rem / 6;                 // 0..16
    const int it6 = rem - dg * 6;            // 0..5
    const int i0  = it6 * 64;
    const bool dgden = (dg == 16);
    const int d0 = dgden ? 0 : 2 * dg;
    const int tid = threadIdx.x;
    const int w = tid >> 6, lane = tid & 63;
    __shared__ u16 A_lds[64 * N];            // raw Z [i][j], chunk-swizzled: jchunk ^= (i&7)
    __shared__ float red[2][12][64];
    const u16* Zh = Zbf + h * (N * N);
    const u16* Xh = Xbf + h * (N * N);
    const float* Yth = Yt + h * (N * N);
    const float* vjd0 = vjT + h * (D * N) + d0 * N;          // d1 row = vjd0 + N
    const float* vkd0 = vkT + h * (D * N) + d0 * N;

    // ---- A-prep (coalesced pure copy): 3072 chunks(short8); 4 iters x 768 thr
    {
#pragma unroll
        for (int it = 0; it < 4; ++it) {
            const int g = it * 768 + tid;        // 0..3071
            const int row = g / 48;
            const int cb = g - row * 48;
            const int jb = cb * 8;
            const int dst = row * N + (jb ^ ((row & 7) << 3));
            *(short8*)&A_lds[dst] = *(const short8*)&Zh[(i0 + row) * N + jb];
        }
    }
    __syncthreads();

    // ---- MFMA main loop: no barriers, k held in accumulators; B ping-pong prefetch
    f32x4 acc0[4][2], acc1[4][2];
#pragma unroll
    for (int fi = 0; fi < 4; ++fi)
#pragma unroll
        for (int fk = 0; fk < 2; ++fk) {
            acc0[fi][fk] = (f32x4){0.f, 0.f, 0.f, 0.f};
            acc1[fi][fk] = (f32x4){0.f, 0.f, 0.f, 0.f};
        }

    const int l15 = lane & 15;
    const int jc = (lane >> 4) * 8;
    const int sw = (l15 & 7) << 3;    // fi*16 keeps row&7 == lane&7
    const int kwb = w * 32 + l15;
    const u16* Br0 = &Xh[(kwb +  0) * N];
    const u16* Br1 = &Xh[(kwb + 16) * N];

    short8 bA[2], bB[2];
    bA[0] = *(const short8*)&Br0[jc];
    bA[1] = *(const short8*)&Br1[jc];

#pragma unroll
    for (int it = 0; it < 6; ++it) {
        const int js0 = it * 2, js1 = it * 2 + 1;
        {   // prefetch js1 B
            const int j = js1 * 32 + jc;
            bB[0] = *(const short8*)&Br0[j];
            bB[1] = *(const short8*)&Br1[j];
        }
#pragma unroll
        for (int half = 0; half < 2; ++half) {
            const int js = it * 2 + half;
            const int j = js * 32 + jc;
            const short8* bcur = half ? bB : bA;
            if (half == 0 && it < 5) { /* placeholder order hint */ }
            // vj broadcast loads (L1-hot; 2 rows adjacent)
            float vv0[8], vv1[8];
            if (!dgden) {
                float4 p0 = *(const float4*)&vjd0[j];
                float4 p1 = *(const float4*)&vjd0[j + 4];
                float4 q0 = *(const float4*)&vjd0[N + j];
                float4 q1 = *(const float4*)&vjd0[N + j + 4];
                vv0[0]=p0.x; vv0[1]=p0.y; vv0[2]=p0.z; vv0[3]=p0.w;
                vv0[4]=p1.x; vv0[5]=p1.y; vv0[6]=p1.z; vv0[7]=p1.w;
                vv1[0]=q0.x; vv1[1]=q0.y; vv1[2]=q0.z; vv1[3]=q0.w;
                vv1[4]=q1.x; vv1[5]=q1.y; vv1[6]=q1.z; vv1[7]=q1.w;
            }
            // A reads (4 per js)
            short8 a[4];
#pragma unroll
            for (int fi = 0; fi < 4; ++fi)
                a[fi] = *(const short8*)&A_lds[(fi * 16 + l15) * N + (j ^ sw)];
            // scale B frags per d-slot in registers
            short8 c00, c01, c10, c11;
            if (dgden) {
                c00 = bcur[0]; c01 = bcur[1]; c10 = bcur[0]; c11 = bcur[1];
            } else {
#pragma unroll
                for (int e = 0; e < 8; ++e) {
                    float x0 = bf2f((u16)bcur[0][e]);
                    float x1 = bf2f((u16)bcur[1][e]);
                    c00[e] = (short)f2bf(x0 * vv0[e]);
                    c01[e] = (short)f2bf(x1 * vv0[e]);
                    c10[e] = (short)f2bf(x0 * vv1[e]);
                    c11[e] = (short)f2bf(x1 * vv1[e]);
                }
            }
            // prefetch next js0 B after consuming bA (only on half==1 path handled below)
            if (half == 1 && it < 5) {
                const int jn = (js1 + 1) * 32 + jc;
                bA[0] = *(const short8*)&Br0[jn];
                bA[1] = *(const short8*)&Br1[jn];
            }
#pragma unroll
            for (int fi = 0; fi < 4; ++fi) {
                acc0[fi][0] = __builtin_amdgcn_mfma_f32_16x16x32_bf16(a[fi], c00, acc0[fi][0], 0, 0, 0);
                acc0[fi][1] = __builtin_amdgcn_mfma_f32_16x16x32_bf16(a[fi], c01, acc0[fi][1], 0, 0, 0);
                acc1[fi][0] = __builtin_amdgcn_mfma_f32_16x16x32_bf16(a[fi], c10, acc1[fi][0], 0, 0, 0);
                acc1[fi][1] = __builtin_amdgcn_mfma_f32_16x16x32_bf16(a[fi], c11, acc1[fi][1], 0, 0, 0);
            }
        }
    }

    // ---- epilogue (merged d0/d1: each Yt value loaded once) ----
    const int rbase = (lane >> 4) << 2;
    float np0[4][4], np1[4][4];
#pragma unroll
    for (int fi = 0; fi < 4; ++fi)
#pragma unroll
        for (int reg = 0; reg < 4; ++reg) { np0[fi][reg] = 0.f; np1[fi][reg] = 0.f; }
#pragma unroll
    for (int fk = 0; fk < 2; ++fk) {
        const int kcol = kwb + fk * 16;
        const float vk0 = dgden ? 1.0f : vkd0[kcol];
        const float vk1 = dgden ? 1.0f : vkd0[N + kcol];
#pragma unroll
        for (int fi = 0; fi < 4; ++fi) {
#pragma unroll
            for (int reg = 0; reg < 4; ++reg) {
                const int irow = i0 + fi * 16 + rbase + reg;
                const float yw = Yth[irow * N + kcol];
                np0[fi][reg] = fmaf(acc0[fi][fk][reg], yw * vk0, np0[fi][reg]);
                np1[fi][reg] = fmaf(acc1[fi][fk][reg], yw * vk1, np1[fi][reg]);
            }
        }
    }
#pragma unroll
    for (int fi = 0; fi < 4; ++fi) {
#pragma unroll
        for (int reg = 0; reg < 4; ++reg) {
            float v0 = np0[fi][reg];
            v0 += __shfl_xor(v0, 1); v0 += __shfl_xor(v0, 2);
            v0 += __shfl_xor(v0, 4); v0 += __shfl_xor(v0, 8);
            np0[fi][reg] = v0;
            float v1 = np1[fi][reg];
            v1 += __shfl_xor(v1, 1); v1 += __shfl_xor(v1, 2);
            v1 += __shfl_xor(v1, 4); v1 += __shfl_xor(v1, 8);
            np1[fi][reg] = v1;
        }
    }
    if (l15 == 0) {
#pragma unroll
        for (int fi = 0; fi < 4; ++fi)
#pragma unroll
            for (int reg = 0; reg < 4; ++reg) {
                red[0][w][fi * 16 + rbase + reg] = np0[fi][reg];
                red[1][w][fi * 16 + rbase + reg] = np1[fi][reg];
            }
    }
    __syncthreads();
    if (tid < 64) {
        float s = 0.f;
#pragma unroll
        for (int ww = 0; ww < 12; ++ww) s += red[0][ww][tid];
        if (!dgden) NumB[h * (N * D) + (i0 + tid) * D + 2 * dg] = s;
        else        DenB[h * N + i0 + tid] = s;
    } else if (tid < 128 && !dgden) {
        const int i = tid - 64;
        float s = 0.f;
#pragma unroll
        for (int ww = 0; ww < 12; ++ww) s += red[1][ww][i];
        NumB[h * (N * D) + (i0 + i) * D + 2 * dg + 1] = s;
    }
}

// ---------------- K6: normalize + fp32 output [n, h*D+d] ----------------
__global__ void out_kernel(const float* __restrict__ NumB, const float* __restrict__ DenB,
                           float* __restrict__ out) {
    int idx = blockIdx.x * 256 + threadIdx.x;  // 0..98303
    int n = idx >> 8;
    int ch = idx & 255;
    int hh = ch >> 5, d = ch & 31;
    float v = NumB[hh * (N * D) + n * D + d] / (DenB[hh * N + n] + EPS);
    out[idx] = v;
}

extern "C" void kernel_launch(void* const* d_in, const int* in_sizes, int n_in,
                              void* d_out, int out_size, void* d_ws, size_t ws_size,
                              hipStream_t stream) {
    const float* hs = (const float*)d_in[0];
    const float* W  = (const float*)d_in[1];
    float* ws = (float*)d_ws;
    float* proj  = ws + PROJ_OFF;
    float* S     = ws + S_OFF;
    float* projT = ws + VJT_OFF;    // vj rows, then vk rows at +H*D*N
    float* mX    = ws + MX_OFF;
    float* mY    = ws + MY_OFF;
    float* mZ    = ws + MZ_OFF;
    float* NumB  = ws + NUM_OFF;
    float* DenB  = ws + DEN_OFF;
    u16*   Xbf   = (u16*)(ws + XBF_OFF);
    u16*   Zbf   = (u16*)(ws + ZBF_OFF);
    float* mXrow = ws + MXROW_OFF;
    float* out = (float*)d_out;

    proj_kernel<<<dim3(20, 6), 256, 0, stream>>>(hs, W, proj, projT);
    scores_kernel<<<dim3(36, 8, 3), 256, 0, stream>>>(proj, S);
    rowmax_kernel<<<dim3(96, 8, 3), 256, 0, stream>>>(S, mXrow, mY, mZ);
    reduce_mx_kernel<<<8, 64, 0, stream>>>(mXrow, mX);
    exp_kernel<<<1728, 256, 0, stream>>>(S, mX, mY, mZ, Xbf, Zbf);
    cubic_mfma<<<dim3(816), 768, 0, stream>>>(Xbf, Zbf, S + HNN, ws + VJT_OFF,
                                              ws + VKT_OFF, NumB, DenB);
    out_kernel<<<(H * N * D) / 256, 256, 0, stream>>>(NumB, DenB, out);
}

// Round 13
// 106.256 us; speedup vs baseline: 1.1736x; 1.1736x over previous
//
#include <hip/hip_runtime.h>
#include <hip/hip_bf16.h>

typedef unsigned short u16;
typedef __attribute__((ext_vector_type(8))) short short8;
typedef __attribute__((ext_vector_type(4))) float f32x4;

#define H 8
#define N 384
#define D 32
#define CIN 256
#define HNN (H * N * N)
#define SCALER 0.17677669529663687f
#define EPS 1e-9f

// workspace float offsets
#define PROJ_OFF 0u              // 5*H*N*D = 491520: a,b,c,vj,vk as [5][H][N][D]
#define S_OFF    491520u         // 3*H*N*N: t=0 XT[k][j], t=1 YT[i][k], t=2 Z[i][j]
#define VJT_OFF  4030464u        // H*D*N = 98304: vj transposed [h][d][n]
#define VKT_OFF  4128768u        // H*D*N
#define MX_OFF   4227072u        // 8
#define MY_OFF   4227080u        // H*N
#define MZ_OFF   4230152u        // H*N
#define NUM_OFF  4233224u        // H*N*D
#define DEN_OFF  4331528u        // H*N
#define XBF_OFF  4334600u        // ushort[H*N*N]: X packed in MFMA-frag order
#define ZBF_OFF  4924424u        // ushort[H*N*N] (Z bf16, row-major)
#define MXROW_OFF 5514248u       // H*N row maxima of X plane

__device__ inline float bf2f(u16 u) {
    union { unsigned int x; float f; } c; c.x = ((unsigned int)u) << 16; return c.f;
}
__device__ inline u16 f2bf(float f) {
    unsigned int x = __float_as_uint(f);
    return (u16)((x + 0x7FFFu + ((x >> 16) & 1u)) >> 16);
}

// ---------------- K1: projection GEMM  wx[n,m] = sum_k hs[n,k]*W[m,k] ----------------
__global__ __launch_bounds__(256) void proj_kernel(const float* __restrict__ hs,
                                                   const float* __restrict__ W,
                                                   float* __restrict__ proj,
                                                   float* __restrict__ projT) {
    __shared__ float hs_s[64][68];
    __shared__ float w_s[64][68];
    const int tid = threadIdx.x;
    const int tx = tid & 15, ty = tid >> 4;
    const int m0 = blockIdx.x * 64, n0 = blockIdx.y * 64;
    float acc[4][4] = {};
    for (int k0 = 0; k0 < CIN; k0 += 64) {
        __syncthreads();
#pragma unroll
        for (int rep = 0; rep < 4; ++rep) {
            int lin = rep * 1024 + tid * 4;
            int rl = lin >> 6, kl = lin & 63;
            float4 hv = *(const float4*)&hs[(n0 + rl) * CIN + k0 + kl];
            hs_s[kl + 0][rl] = hv.x; hs_s[kl + 1][rl] = hv.y;
            hs_s[kl + 2][rl] = hv.z; hs_s[kl + 3][rl] = hv.w;
            float4 wv = *(const float4*)&W[(m0 + rl) * CIN + k0 + kl];
            w_s[kl + 0][rl] = wv.x; w_s[kl + 1][rl] = wv.y;
            w_s[kl + 2][rl] = wv.z; w_s[kl + 3][rl] = wv.w;
        }
        __syncthreads();
#pragma unroll 16
        for (int kk = 0; kk < 64; ++kk) {
            float4 a4 = *(const float4*)&hs_s[kk][ty * 4];
            float4 b4 = *(const float4*)&w_s[kk][tx * 4];
            float av[4] = {a4.x, a4.y, a4.z, a4.w};
            float bv[4] = {b4.x, b4.y, b4.z, b4.w};
#pragma unroll
            for (int a_ = 0; a_ < 4; ++a_) {
#pragma unroll
                for (int b_ = 0; b_ < 4; ++b_) {
                    acc[a_][b_] = fmaf(av[a_], bv[b_], acc[a_][b_]);
                }
            }
        }
    }
#pragma unroll
    for (int a_ = 0; a_ < 4; ++a_) {
        int n = n0 + ty * 4 + a_;
#pragma unroll
        for (int b_ = 0; b_ < 4; ++b_) {
            int m = m0 + tx * 4 + b_;
            int s = m >> 8, hh = (m >> 5) & 7, d = m & 31;
            proj[s * (H * N * D) + hh * (N * D) + n * D + d] = acc[a_][b_];
            if (s >= 3) projT[(s - 3) * (H * D * N) + hh * (D * N) + d * N + n] = acc[a_][b_];
        }
    }
}

// ---------------- K2: scores ----------------
// t=0: XT[k,j] = c_k . b_j ; t=1: YT[i,k] = a_i . c_k ; t=2: Z[i,j] = a_i . b_j
// one 64x64 tile per block
__global__ __launch_bounds__(256) void scores_kernel(const float* __restrict__ proj,
                                                     float* __restrict__ S) {
    __shared__ float LsT[32][68];
    __shared__ float RsT[32][68];
    const int tid = threadIdx.x, tx = tid & 15, ty = tid >> 4;
    const int rt = blockIdx.x % 6, ct = blockIdx.x / 6;
    const int r0 = rt * 64, c0 = ct * 64;
    const int h = blockIdx.y;
    const int t = blockIdx.z;
    const int Lidx = (t == 0) ? 2 : 0;
    const int Ridx = (t == 1) ? 2 : 1;
    const float* Lp = proj + Lidx * (H * N * D) + h * (N * D);
    const float* Rp = proj + Ridx * (H * N * D) + h * (N * D);
    float* Sp = S + t * HNN + h * (N * N);
    {
        int i = tid >> 2, d8 = (tid & 3) * 8;
        float4 v0 = *(const float4*)&Lp[(r0 + i) * D + d8];
        float4 v1 = *(const float4*)&Lp[(r0 + i) * D + d8 + 4];
        LsT[d8 + 0][i] = v0.x; LsT[d8 + 1][i] = v0.y; LsT[d8 + 2][i] = v0.z; LsT[d8 + 3][i] = v0.w;
        LsT[d8 + 4][i] = v1.x; LsT[d8 + 5][i] = v1.y; LsT[d8 + 6][i] = v1.z; LsT[d8 + 7][i] = v1.w;
        float4 w0 = *(const float4*)&Rp[(c0 + i) * D + d8];
        float4 w1 = *(const float4*)&Rp[(c0 + i) * D + d8 + 4];
        RsT[d8 + 0][i] = w0.x; RsT[d8 + 1][i] = w0.y; RsT[d8 + 2][i] = w0.z; RsT[d8 + 3][i] = w0.w;
        RsT[d8 + 4][i] = w1.x; RsT[d8 + 5][i] = w1.y; RsT[d8 + 6][i] = w1.z; RsT[d8 + 7][i] = w1.w;
    }
    __syncthreads();
    float acc[4][4] = {};
#pragma unroll
    for (int dd = 0; dd < 32; ++dd) {
        float4 l4 = *(const float4*)&LsT[dd][ty * 4];
        float4 r4 = *(const float4*)&RsT[dd][tx * 4];
        float lv[4] = {l4.x, l4.y, l4.z, l4.w};
        float rv[4] = {r4.x, r4.y, r4.z, r4.w};
#pragma unroll
        for (int a_ = 0; a_ < 4; ++a_) {
#pragma unroll
            for (int b_ = 0; b_ < 4; ++b_) {
                acc[a_][b_] = fmaf(lv[a_], rv[b_], acc[a_][b_]);
            }
        }
    }
#pragma unroll
    for (int a_ = 0; a_ < 4; ++a_) {
        float4 o;
        o.x = acc[a_][0] * SCALER; o.y = acc[a_][1] * SCALER;
        o.z = acc[a_][2] * SCALER; o.w = acc[a_][3] * SCALER;
        *(float4*)&Sp[(r0 + ty * 4 + a_) * N + c0 + tx * 4] = o;
    }
}

// ---------------- K3: row maxima for all three planes ----------------
__global__ void rowmax_kernel(const float* __restrict__ S, float* __restrict__ mXrow,
                              float* __restrict__ mY, float* __restrict__ mZ) {
    const int z = blockIdx.z;
    const int h = blockIdx.y;
    const int r = blockIdx.x * 4 + (threadIdx.x >> 6);
    const int lane = threadIdx.x & 63;
    const float* row = S + z * HNN + h * (N * N) + r * N;
    float m = -3.0e38f;
    for (int q = lane; q < N; q += 64) m = fmaxf(m, row[q]);
#pragma unroll
    for (int off = 32; off; off >>= 1) m = fmaxf(m, __shfl_down(m, off));
    if (lane == 0) (z == 0 ? mXrow : (z == 1 ? mY : mZ))[h * N + r] = m;
}

// reduce mXrow[h][0..N) -> mX[h]; grid 8 x 64 threads
__global__ void reduce_mx_kernel(const float* __restrict__ mXrow, float* __restrict__ mX) {
    const int h = blockIdx.x;
    const int lane = threadIdx.x;
    float m = -3.0e38f;
    for (int q = lane; q < N; q += 64) m = fmaxf(m, mXrow[h * N + q]);
#pragma unroll
    for (int off = 32; off; off >>= 1) m = fmaxf(m, __shfl_down(m, off));
    if (lane == 0) mX[h] = m;
}

// ---------------- K4: exp.  t=1 writes f32 in place; t=0 -> packed bf16, t=2 -> row bf16 ----------------
// Xpack layout: [h][kt=k/16][jt=j/32][lane][8], lane = (k&15) | ((j>>3)&3)<<4  (B-frag order)
__global__ void exp_kernel(float* __restrict__ S, const float* __restrict__ mX,
                           const float* __restrict__ mY, const float* __restrict__ mZ,
                           u16* __restrict__ Xbf, u16* __restrict__ Zbf) {
    int f8 = blockIdx.x * 256 + threadIdx.x;  // 442368 total
    int flat = f8 * 8;
    int t = flat / HNN;
    int rem = flat - t * HNN;
    int h = rem / (N * N);
    int rc = rem - h * (N * N);
    int r = rc / N;
    int c = rc - r * N;
    float m = (t == 0) ? mX[h] : ((t == 1) ? mY[h * N + r] : mZ[h * N + r]);
    float4 v0 = *(float4*)&S[flat];
    float4 v1 = *(float4*)&S[flat + 4];
    float e[8] = {__expf(v0.x - m), __expf(v0.y - m), __expf(v0.z - m), __expf(v0.w - m),
                  __expf(v1.x - m), __expf(v1.y - m), __expf(v1.z - m), __expf(v1.w - m)};
    if (t == 1) {
        float4 o0 = {e[0], e[1], e[2], e[3]}, o1 = {e[4], e[5], e[6], e[7]};
        *(float4*)&S[flat] = o0;
        *(float4*)&S[flat + 4] = o1;
    } else {
        short8 ov;
#pragma unroll
        for (int q = 0; q < 8; ++q) ov[q] = (short)f2bf(e[q]);
        if (t == 0) {
            const int kt = r >> 4, jt = c >> 5;
            const int lanep = (r & 15) | (((c >> 3) & 3) << 4);
            u16* dst = Xbf + (((h * 24 + kt) * 12 + jt) << 9) + lanep * 8;
            *(short8*)dst = ov;
        } else {
            u16* dst = Zbf + h * (N * N) + rc;
            *(short8*)dst = ov;
        }
    }
}

// ---------------- K5: cubic contraction via MFMA bf16, v11 (r11 + packed-B coalesced loads) ----------------
// block = (h, i-tile of 64, d-group of 2). 768 thr = 12 waves, wave owns 32 k (= 2 k-tiles).
// B loads: packed frag order -> 64 lanes x 16B = 1KB contiguous burst per frag (was 16
// scattered lines). Per js: 8 A LDS reads + 2 coalesced B loads + 16 MFMAs.
// LDS: two scaled A tiles 96 KB + red 6 KB -> 1 block/CU, 12 waves (3/SIMD).
__global__ __launch_bounds__(768, 3) void cubic_mfma(
        const u16* __restrict__ Xbf, const u16* __restrict__ Zbf,
        const float* __restrict__ Yt, const float* __restrict__ vjT,
        const float* __restrict__ vkT, float* __restrict__ NumB,
        float* __restrict__ DenB) {
    const int orig = blockIdx.x;             // 0..815 (816 = 8 x 102, bijective)
    const int wg = (orig & 7) * 102 + (orig >> 3);
    const int h   = wg / 102;                // one head per XCD
    const int rem = wg - h * 102;
    const int dg  = rem / 6;                 // 0..16
    const int it6 = rem - dg * 6;            // 0..5
    const int i0  = it6 * 64;
    const bool dgden = (dg == 16);
    const int d0 = dgden ? 0 : 2 * dg;
    const int d1 = dgden ? 0 : 2 * dg + 1;
    const int tid = threadIdx.x;
    const int w = tid >> 6, lane = tid & 63;
    __shared__ u16 A_lds[2 * 64 * N];        // [t][i][j], chunk-swizzled: jchunk ^= (i&7)
    __shared__ float red[2][12][64];
    u16* A0 = A_lds;
    u16* A1 = A_lds + 64 * N;
    const u16* Zh = Zbf + h * (N * N);
    const float* Yth = Yt + h * (N * N);
    const float* vjd0 = vjT + h * (D * N) + d0 * N;
    const float* vjd1 = vjT + h * (D * N) + d1 * N;
    const float* vkd0 = vkT + h * (D * N) + d0 * N;
    const float* vkd1 = vkT + h * (D * N) + d1 * N;

    // ---- A-prep (coalesced): 3072 chunks(short8); 4 iters x 768 thr; writes both tiles
    {
#pragma unroll
        for (int it = 0; it < 4; ++it) {
            const int g = it * 768 + tid;        // 0..3071
            const int row = g / 48;
            const int cb = g - row * 48;
            const int jb = cb * 8;
            const int dst = row * N + (jb ^ ((row & 7) << 3));
            short8 zv = *(const short8*)&Zh[(i0 + row) * N + jb];
            if (dgden) {
                *(short8*)&A0[dst] = zv;
                *(short8*)&A1[dst] = zv;
            } else {
                float4 p0 = *(const float4*)&vjd0[jb];
                float4 p1 = *(const float4*)&vjd0[jb + 4];
                float4 q0 = *(const float4*)&vjd1[jb];
                float4 q1 = *(const float4*)&vjd1[jb + 4];
                float v0[8] = {p0.x, p0.y, p0.z, p0.w, p1.x, p1.y, p1.z, p1.w};
                float v1[8] = {q0.x, q0.y, q0.z, q0.w, q1.x, q1.y, q1.z, q1.w};
                short8 o0, o1;
#pragma unroll
                for (int e = 0; e < 8; ++e) {
                    float zf = bf2f((u16)zv[e]);
                    o0[e] = (short)f2bf(zf * v0[e]);
                    o1[e] = (short)f2bf(zf * v1[e]);
                }
                *(short8*)&A0[dst] = o0;
                *(short8*)&A1[dst] = o1;
            }
        }
    }
    __syncthreads();

    // ---- MFMA main loop: no barriers, k held in accumulators; B ping-pong prefetch
    f32x4 acc0[4][2], acc1[4][2];
#pragma unroll
    for (int fi = 0; fi < 4; ++fi)
#pragma unroll
        for (int fk = 0; fk < 2; ++fk) {
            acc0[fi][fk] = (f32x4){0.f, 0.f, 0.f, 0.f};
            acc1[fi][fk] = (f32x4){0.f, 0.f, 0.f, 0.f};
        }

    const int l15 = lane & 15;
    const int jc = (lane >> 4) * 8;
    const int sw = (l15 & 7) << 3;    // fi*16 keeps row&7 == lane&7
    const int kwb = w * 32 + l15;
    // packed-B bases: wave w covers k-tiles 2w and 2w+1; frag (kt, jt) at (kt*12+jt)*512
    const u16* Bp = Xbf + ((h * 24 + w * 2) * 12 << 9) + lane * 8;
    const int FST = 512;              // u16 per frag
    const int KT1 = 12 * 512;         // second k-tile offset

    short8 bA[2], bB[2];
    bA[0] = *(const short8*)&Bp[0];
    bA[1] = *(const short8*)&Bp[KT1];

#pragma unroll
    for (int it = 0; it < 6; ++it) {
        const int js0 = it * 2, js1 = it * 2 + 1;
        {   // prefetch js1 (coalesced 1KB bursts)
            bB[0] = *(const short8*)&Bp[js1 * FST];
            bB[1] = *(const short8*)&Bp[KT1 + js1 * FST];
        }
        {   // compute js0 with bA
            const int j = js0 * 32 + jc;
            short8 a0[4], a1[4];
#pragma unroll
            for (int fi = 0; fi < 4; ++fi) {
                a0[fi] = *(const short8*)&A0[(fi * 16 + l15) * N + (j ^ sw)];
                a1[fi] = *(const short8*)&A1[(fi * 16 + l15) * N + (j ^ sw)];
            }
#pragma unroll
            for (int fk = 0; fk < 2; ++fk) {
#pragma unroll
                for (int fi = 0; fi < 4; ++fi) {
                    acc0[fi][fk] = __builtin_amdgcn_mfma_f32_16x16x32_bf16(a0[fi], bA[fk], acc0[fi][fk], 0, 0, 0);
                    acc1[fi][fk] = __builtin_amdgcn_mfma_f32_16x16x32_bf16(a1[fi], bA[fk], acc1[fi][fk], 0, 0, 0);
                }
            }
        }
        if (it < 5) {   // prefetch next js0
            bA[0] = *(const short8*)&Bp[(js1 + 1) * FST];
            bA[1] = *(const short8*)&Bp[KT1 + (js1 + 1) * FST];
        }
        {   // compute js1 with bB
            const int j = js1 * 32 + jc;
            short8 a0[4], a1[4];
#pragma unroll
            for (int fi = 0; fi < 4; ++fi) {
                a0[fi] = *(const short8*)&A0[(fi * 16 + l15) * N + (j ^ sw)];
                a1[fi] = *(const short8*)&A1[(fi * 16 + l15) * N + (j ^ sw)];
            }
#pragma unroll
            for (int fk = 0; fk < 2; ++fk) {
#pragma unroll
                for (int fi = 0; fi < 4; ++fi) {
                    acc0[fi][fk] = __builtin_amdgcn_mfma_f32_16x16x32_bf16(a0[fi], bB[fk], acc0[fi][fk], 0, 0, 0);
                    acc1[fi][fk] = __builtin_amdgcn_mfma_f32_16x16x32_bf16(a1[fi], bB[fk], acc1[fi][fk], 0, 0, 0);
                }
            }
        }
    }

    // ---- epilogue: weight by YT[i,k]*vk[k,d], reduce over k; d0 then d1 (caps reg peak)
    const int rbase = (lane >> 4) << 2;
    {   // d0
        float np[4][4];
#pragma unroll
        for (int fi = 0; fi < 4; ++fi)
#pragma unroll
            for (int reg = 0; reg < 4; ++reg) np[fi][reg] = 0.f;
#pragma unroll
        for (int fk = 0; fk < 2; ++fk) {
            const int kcol = kwb + fk * 16;
            const float vkv = dgden ? 1.0f : vkd0[kcol];
#pragma unroll
            for (int fi = 0; fi < 4; ++fi) {
#pragma unroll
                for (int reg = 0; reg < 4; ++reg) {
                    const int irow = i0 + fi * 16 + rbase + reg;
                    const float wgt = Yth[irow * N + kcol] * vkv;
                    np[fi][reg] = fmaf(acc0[fi][fk][reg], wgt, np[fi][reg]);
                }
            }
        }
#pragma unroll
        for (int fi = 0; fi < 4; ++fi) {
#pragma unroll
            for (int reg = 0; reg < 4; ++reg) {
                float v = np[fi][reg];
                v += __shfl_xor(v, 1); v += __shfl_xor(v, 2);
                v += __shfl_xor(v, 4); v += __shfl_xor(v, 8);
                np[fi][reg] = v;
            }
        }
        if (l15 == 0) {
#pragma unroll
            for (int fi = 0; fi < 4; ++fi)
#pragma unroll
                for (int reg = 0; reg < 4; ++reg)
                    red[0][w][fi * 16 + rbase + reg] = np[fi][reg];
        }
    }
    {   // d1
        float np[4][4];
#pragma unroll
        for (int fi = 0; fi < 4; ++fi)
#pragma unroll
            for (int reg = 0; reg < 4; ++reg) np[fi][reg] = 0.f;
#pragma unroll
        for (int fk = 0; fk < 2; ++fk) {
            const int kcol = kwb + fk * 16;
            const float vkv = dgden ? 1.0f : vkd1[kcol];
#pragma unroll
            for (int fi = 0; fi < 4; ++fi) {
#pragma unroll
                for (int reg = 0; reg < 4; ++reg) {
                    const int irow = i0 + fi * 16 + rbase + reg;
                    const float wgt = Yth[irow * N + kcol] * vkv;
                    np[fi][reg] = fmaf(acc1[fi][fk][reg], wgt, np[fi][reg]);
                }
            }
        }
#pragma unroll
        for (int fi = 0; fi < 4; ++fi) {
#pragma unroll
            for (int reg = 0; reg < 4; ++reg) {
                float v = np[fi][reg];
                v += __shfl_xor(v, 1); v += __shfl_xor(v, 2);
                v += __shfl_xor(v, 4); v += __shfl_xor(v, 8);
                np[fi][reg] = v;
            }
        }
        if (l15 == 0) {
#pragma unroll
            for (int fi = 0; fi < 4; ++fi)
#pragma unroll
                for (int reg = 0; reg < 4; ++reg)
                    red[1][w][fi * 16 + rbase + reg] = np[fi][reg];
        }
    }
    __syncthreads();
    if (tid < 64) {
        float s = 0.f;
#pragma unroll
        for (int ww = 0; ww < 12; ++ww) s += red[0][ww][tid];
        if (!dgden) NumB[h * (N * D) + (i0 + tid) * D + 2 * dg] = s;
        else        DenB[h * N + i0 + tid] = s;
    } else if (tid < 128 && !dgden) {
        const int i = tid - 64;
        float s = 0.f;
#pragma unroll
        for (int ww = 0; ww < 12; ++ww) s += red[1][ww][i];
        NumB[h * (N * D) + (i0 + i) * D + 2 * dg + 1] = s;
    }
}

// ---------------- K6: normalize + fp32 output [n, h*D+d] ----------------
__global__ void out_kernel(const float* __restrict__ NumB, const float* __restrict__ DenB,
                           float* __restrict__ out) {
    int idx = blockIdx.x * 256 + threadIdx.x;  // 0..98303
    int n = idx >> 8;
    int ch = idx & 255;
    int hh = ch >> 5, d = ch & 31;
    float v = NumB[hh * (N * D) + n * D + d] / (DenB[hh * N + n] + EPS);
    out[idx] = v;
}

extern "C" void kernel_launch(void* const* d_in, const int* in_sizes, int n_in,
                              void* d_out, int out_size, void* d_ws, size_t ws_size,
                              hipStream_t stream) {
    const float* hs = (const float*)d_in[0];
    const float* W  = (const float*)d_in[1];
    float* ws = (float*)d_ws;
    float* proj  = ws + PROJ_OFF;
    float* S     = ws + S_OFF;
    float* projT = ws + VJT_OFF;    // vj rows, then vk rows at +H*D*N
    float* mX    = ws + MX_OFF;
    float* mY    = ws + MY_OFF;
    float* mZ    = ws + MZ_OFF;
    float* NumB  = ws + NUM_OFF;
    float* DenB  = ws + DEN_OFF;
    u16*   Xbf   = (u16*)(ws + XBF_OFF);
    u16*   Zbf   = (u16*)(ws + ZBF_OFF);
    float* mXrow = ws + MXROW_OFF;
    float* out = (float*)d_out;

    proj_kernel<<<dim3(20, 6), 256, 0, stream>>>(hs, W, proj, projT);
    scores_kernel<<<dim3(36, 8, 3), 256, 0, stream>>>(proj, S);
    rowmax_kernel<<<dim3(96, 8, 3), 256, 0, stream>>>(S, mXrow, mY, mZ);
    reduce_mx_kernel<<<8, 64, 0, stream>>>(mXrow, mX);
    exp_kernel<<<1728, 256, 0, stream>>>(S, mX, mY, mZ, Xbf, Zbf);
    cubic_mfma<<<dim3(816), 768, 0, stream>>>(Xbf, Zbf, S + HNN, ws + VJT_OFF,
                                              ws + VKT_OFF, NumB, DenB);
    out_kernel<<<(H * N * D) / 256, 256, 0, stream>>>(NumB, DenB, out);
}